// Round 6
// baseline (75.733 us; speedup 1.0000x reference)
//
#include <hip/hip_runtime.h>

typedef __attribute__((ext_vector_type(8))) _Float16 half8;
typedef __attribute__((ext_vector_type(4))) _Float16 half4;
typedef __attribute__((ext_vector_type(4))) float f32x4;
typedef __attribute__((ext_vector_type(16))) float f32x16;
#if __has_builtin(__builtin_amdgcn_cvt_pkrtz)
typedef __attribute__((ext_vector_type(2))) __fp16 fp16x2;
#endif

#define ALPHA 0.2f
#define LOG2E 1.44269504f

__device__ __forceinline__ void gload_lds16(const void* g, void* l) {
  __builtin_amdgcn_global_load_lds((const __attribute__((address_space(1))) unsigned int*)g,
                                   (__attribute__((address_space(3))) unsigned int*)l, 16, 0, 0);
}

__device__ __forceinline__ float fexp2(float x) {
#if __has_builtin(__builtin_amdgcn_exp2f)
  return __builtin_amdgcn_exp2f(x);
#else
  return exp2f(x);
#endif
}

// ---------------- K0a: W fp32 -> fp16, PRE-SWIZZLED (unit8 XOR (n&7)) ----------------
__global__ __launch_bounds__(256) void k_convW(const float* __restrict__ W,
                                               _Float16* __restrict__ W16) {
  int idx4 = blockIdx.x * 256 + threadIdx.x;  // half4 unit
  int n = idx4 >> 7;                          // row 0..255
  int q = idx4 & 127;                         // half4 within row
  float4 v = *reinterpret_cast<const float4*>(W + n * 512 + q * 4);
  half4 hv = {(_Float16)v.x, (_Float16)v.y, (_Float16)v.z, (_Float16)v.w};
  int kp = (q * 4) ^ ((n & 7) << 3);          // swizzle within 64-elem blocks
  *reinterpret_cast<half4*>(W16 + n * 512 + kp) = hv;
}

// ---------------- K0b: u = W^T a  (8 blocks, coalesced over k) ----------------
__global__ __launch_bounds__(256) void k_uvec(const float* __restrict__ W,
                                              const float* __restrict__ a1,
                                              const float* __restrict__ a2,
                                              float* __restrict__ u1,
                                              float* __restrict__ u2) {
  __shared__ float p1[4][64], p2[4][64];
  int t = threadIdx.x;
  int l = t & 63, g = t >> 6;
  int k = blockIdx.x * 64 + l;
  float x1 = 0.f, x2 = 0.f;
  for (int o = g * 64; o < g * 64 + 64; ++o) {
    float wv = W[o * 512 + k];
    x1 += wv * a1[o];
    x2 += wv * a2[o];
  }
  p1[g][l] = x1; p2[g][l] = x2;
  __syncthreads();
  if (g == 0) {
    u1[k] = p1[0][l] + p1[1][l] + p1[2][l] + p1[3][l];
    u2[k] = p2[0][l] + p2[1][l] + p2[2][l] + p2[3][l];
  }
}

// ---------------- K2: Wh GEMM + fused s1/s2 (R2-proven structure, do not touch) ----------------
// block: 32 rows x 256 cols, 4 waves (each 32x64), 512 blocks (2/CU)
__global__ __launch_bounds__(256) void k_gemm_wh(const float* __restrict__ h,
                                                 const _Float16* __restrict__ W16,
                                                 const float* __restrict__ u1,
                                                 const float* __restrict__ u2,
                                                 float* __restrict__ s1o,
                                                 float* __restrict__ s2o,
                                                 _Float16* __restrict__ WhT) {
  __shared__ _Float16 Ab[2][32 * 64];    // 4 KB each, swizzled (reg-staged)
  __shared__ _Float16 Bb[2][256 * 64];   // 32 KB each, linear copy of pre-swizzled W16
  const int t = threadIdx.x, lane = t & 63, w = t >> 6;
  const int i0 = blockIdx.x * 32;        // global row 0..16383
  const int b = i0 >> 11, n0 = i0 & 2047;
  const int ar = t >> 3, au = t & 7;     // A-stage: row 0..31, 8-float chunk 0..7
  const float* hrow = h + (size_t)(i0 + ar) * 512 + au * 8;

  f32x4 acc[2][4];
#pragma unroll
  for (int mi = 0; mi < 2; ++mi)
#pragma unroll
    for (int ni = 0; ni < 4; ++ni) acc[mi][ni] = (f32x4){0.f, 0.f, 0.f, 0.f};

  // prologue: load A(0) regs, stage B(0) via global_load_lds
  float4 aR0 = *reinterpret_cast<const float4*>(hrow);
  float4 aR1 = *reinterpret_cast<const float4*>(hrow + 4);
#pragma unroll
  for (int q = 0; q < 8; ++q) {
    int idx = (q * 4 + w) * 64 + lane;
    int nn = idx >> 3, uu = idx & 7;
    gload_lds16(W16 + nn * 512 + uu * 8, (char*)&Bb[0][0] + idx * 16);
  }
  float x1 = 0.f, x2 = 0.f;

  for (int kt = 0; kt < 8; ++kt) {
    const int cur = kt & 1;
    // ds_write A(kt) (+ fused s1/s2 partials on the same registers)
    {
      half8 av;
      av[0] = (_Float16)aR0.x; av[1] = (_Float16)aR0.y;
      av[2] = (_Float16)aR0.z; av[3] = (_Float16)aR0.w;
      av[4] = (_Float16)aR1.x; av[5] = (_Float16)aR1.y;
      av[6] = (_Float16)aR1.z; av[7] = (_Float16)aR1.w;
      *reinterpret_cast<half8*>((char*)&Ab[cur][0] + ar * 128 + ((au * 16) ^ ((ar & 7) << 4))) = av;
      const float* up1 = u1 + kt * 64 + au * 8;
      const float* up2 = u2 + kt * 64 + au * 8;
      float4 u1a = *reinterpret_cast<const float4*>(up1);
      float4 u1b = *reinterpret_cast<const float4*>(up1 + 4);
      float4 u2a = *reinterpret_cast<const float4*>(up2);
      float4 u2b = *reinterpret_cast<const float4*>(up2 + 4);
      x1 += aR0.x * u1a.x + aR0.y * u1a.y + aR0.z * u1a.z + aR0.w * u1a.w
          + aR1.x * u1b.x + aR1.y * u1b.y + aR1.z * u1b.z + aR1.w * u1b.w;
      x2 += aR0.x * u2a.x + aR0.y * u2a.y + aR0.z * u2a.z + aR0.w * u2a.w
          + aR1.x * u2b.x + aR1.y * u2b.y + aR1.z * u2b.z + aR1.w * u2b.w;
    }
    __syncthreads();  // A(kt) visible; B(kt) loads drained
    if (kt < 7) {     // prefetch tile kt+1 (lands during compute below)
      const int k0 = (kt + 1) * 64;
      aR0 = *reinterpret_cast<const float4*>(hrow + k0);
      aR1 = *reinterpret_cast<const float4*>(hrow + k0 + 4);
#pragma unroll
      for (int q = 0; q < 8; ++q) {
        int idx = (q * 4 + w) * 64 + lane;
        int nn = idx >> 3, uu = idx & 7;
        gload_lds16(W16 + nn * 512 + k0 + uu * 8, (char*)&Bb[cur ^ 1][0] + idx * 16);
      }
    }
    // compute tile kt
    const char* Ac = (const char*)&Ab[cur][0];
    const char* Bc = (const char*)&Bb[cur][0];
#pragma unroll
    for (int kk = 0; kk < 2; ++kk) {
      const int jb = (lane >> 4) * 16 + kk * 64;
      half8 afr[2];
#pragma unroll
      for (int mi = 0; mi < 2; ++mi) {
        int rr = (lane & 15) + 16 * mi;
        afr[mi] = *reinterpret_cast<const half8*>(Ac + rr * 128 + (jb ^ ((rr & 7) << 4)));
      }
#pragma unroll
      for (int ni = 0; ni < 4; ++ni) {
        int nn = 64 * w + 16 * ni + (lane & 15);
        half8 bfr = *reinterpret_cast<const half8*>(Bc + nn * 128 + (jb ^ ((nn & 7) << 4)));
#pragma unroll
        for (int mi = 0; mi < 2; ++mi)
          acc[mi][ni] = __builtin_amdgcn_mfma_f32_16x16x32_f16(afr[mi], bfr, acc[mi][ni], 0, 0, 0);
      }
    }
  }
  // s1/s2: reduce over the 8 threads sharing a row (contiguous lanes)
  x1 += __shfl_xor(x1, 1); x1 += __shfl_xor(x1, 2); x1 += __shfl_xor(x1, 4);
  x2 += __shfl_xor(x2, 1); x2 += __shfl_xor(x2, 2); x2 += __shfl_xor(x2, 4);
  if (au == 0) { s1o[i0 + ar] = x1; s2o[i0 + ar] = x2; }
  // epilogue: pre-swizzled WhT store (unit8 XOR (c&7), within 64-n blocks)
  _Float16* whtb = WhT + (size_t)b * 256 * 2048;
#pragma unroll
  for (int mi = 0; mi < 2; ++mi)
#pragma unroll
    for (int ni = 0; ni < 4; ++ni) {
      int c = 64 * w + 16 * ni + (lane & 15);
      int nb = n0 + 16 * mi + (lane >> 4) * 4;
      int np = nb ^ ((c & 7) << 3);
      f32x4 a = acc[mi][ni];
      half4 hv = {(_Float16)a[0], (_Float16)a[1], (_Float16)a[2], (_Float16)a[3]};
      *reinterpret_cast<half4*>(whtb + (size_t)c * 2048 + np) = hv;
    }
}

// ---------------- K3: fused softmax(P) @ Wh + ELU, 32x32x16 MFMA ----------------
// grid 256 (bid&7 = batch -> XCD affinity; bid>>3 = 64-row block), 512 thr = 8 waves
// (2 rg x 4 cg), wave = 32 rows x 64 cols. B triple-buffered (counted vmcnt(4)),
// P double-buffered, s2 staged+scaled in LDS, per-batch max in-block.
__global__ __launch_bounds__(512) void k_attn(const _Float16* __restrict__ WhT,
                                              const float* __restrict__ s1,
                                              const float* __restrict__ s2,
                                              float* __restrict__ out) {
  __shared__ _Float16 Bb[3][256 * 64];  // 32 KB each
  __shared__ _Float16 Pb[2][64 * 64];   // 8 KB each
  __shared__ float s2s[2048];
  __shared__ float red[8];
  __shared__ float d_lds[64];
  const int t = threadIdx.x, lane = t & 63, w = t >> 6;
  const int rg = w >> 2, cg = w & 3;
  const int b = blockIdx.x & 7;
  const int i0 = (blockIdx.x >> 3) * 64;
  const _Float16* whtb = WhT + (size_t)b * 256 * 2048;
  const int pr = t >> 3, pj8 = t & 7;  // P-build: row 0..63, 8-j chunk 0..7
  const float s1v = s1[b * 2048 + i0 + pr];

  // stage s2 (scaled by log2e) + block-wide max
  float4 sv4 = *reinterpret_cast<const float4*>(s2 + b * 2048 + t * 4);
  float m0 = fmaxf(fmaxf(sv4.x, sv4.y), fmaxf(sv4.z, sv4.w));
  *reinterpret_cast<float4*>(&s2s[t * 4]) =
      make_float4(sv4.x * LOG2E, sv4.y * LOG2E, sv4.z * LOG2E, sv4.w * LOG2E);
#pragma unroll
  for (int off = 32; off >= 1; off >>= 1) m0 = fmaxf(m0, __shfl_xor(m0, off));
  if (lane == 0) red[w] = m0;
  __syncthreads();  // full drain: clean vmcnt slate; s2s/red visible
  float smaxL;
  {
    float mm = red[0];
#pragma unroll
    for (int i = 1; i < 8; ++i) mm = fmaxf(mm, red[i]);
    smaxL = mm * LOG2E;
  }
  const float s1L = LOG2E * s1v;
  const float e0L = s1L + smaxL;
  const float mrowL = fmaxf(e0L, ALPHA * e0L);  // closed-form row max (LR monotonic)
  const float C1 = s1L - mrowL;
  const float C2 = fmaf(ALPHA, s1L, -mrowL);
  const int pwoff = pr * 128 + ((pj8 * 16) ^ ((pr & 7) << 4));
  half8 onesb;
  {
    _Float16 ov = ((lane & 31) == 0) ? (_Float16)1.0f : (_Float16)0.0f;
#pragma unroll
    for (int x = 0; x < 8; ++x) onesb[x] = ov;
  }
  f32x16 acc[2];
  acc[0] = (f32x16)(0.f);
  acc[1] = (f32x16)(0.f);
  f32x16 accd = (f32x16)(0.f);

  // build P(0)
  {
    float4 sa = *reinterpret_cast<const float4*>(&s2s[pj8 * 8]);
    float4 sb = *reinterpret_cast<const float4*>(&s2s[pj8 * 8 + 4]);
    float p0 = fexp2(fmaxf(C1 + sa.x, fmaf(ALPHA, sa.x, C2)));
    float p1 = fexp2(fmaxf(C1 + sa.y, fmaf(ALPHA, sa.y, C2)));
    float p2 = fexp2(fmaxf(C1 + sa.z, fmaf(ALPHA, sa.z, C2)));
    float p3 = fexp2(fmaxf(C1 + sa.w, fmaf(ALPHA, sa.w, C2)));
    float p4 = fexp2(fmaxf(C1 + sb.x, fmaf(ALPHA, sb.x, C2)));
    float p5 = fexp2(fmaxf(C1 + sb.y, fmaf(ALPHA, sb.y, C2)));
    float p6 = fexp2(fmaxf(C1 + sb.z, fmaf(ALPHA, sb.z, C2)));
    float p7 = fexp2(fmaxf(C1 + sb.w, fmaf(ALPHA, sb.w, C2)));
    half8 ph;
#if __has_builtin(__builtin_amdgcn_cvt_pkrtz)
    fp16x2 q0 = __builtin_amdgcn_cvt_pkrtz(p0, p1);
    fp16x2 q1 = __builtin_amdgcn_cvt_pkrtz(p2, p3);
    fp16x2 q2 = __builtin_amdgcn_cvt_pkrtz(p4, p5);
    fp16x2 q3 = __builtin_amdgcn_cvt_pkrtz(p6, p7);
    ph[0] = (_Float16)q0[0]; ph[1] = (_Float16)q0[1];
    ph[2] = (_Float16)q1[0]; ph[3] = (_Float16)q1[1];
    ph[4] = (_Float16)q2[0]; ph[5] = (_Float16)q2[1];
    ph[6] = (_Float16)q3[0]; ph[7] = (_Float16)q3[1];
#else
    ph[0] = (_Float16)p0; ph[1] = (_Float16)p1; ph[2] = (_Float16)p2; ph[3] = (_Float16)p3;
    ph[4] = (_Float16)p4; ph[5] = (_Float16)p5; ph[6] = (_Float16)p6; ph[7] = (_Float16)p7;
#endif
    *reinterpret_cast<half8*>((char*)&Pb[0][0] + pwoff) = ph;
  }
  // issue B(0), B(1): 4 gload_lds per thread per tile
#pragma unroll
  for (int x = 0; x < 2; ++x)
#pragma unroll
    for (int q = 0; q < 4; ++q) {
      int idx = q * 512 + t;
      int cl = idx >> 3, uu = idx & 7;
      gload_lds16(whtb + (size_t)cl * 2048 + x * 64 + uu * 8, (char*)&Bb[x][0] + idx * 16);
    }

  for (int jt = 0; jt < 32; ++jt) {
    // B(jt) landed (own 4 loads beyond the 4 in flight for jt+1); P/ds writes visible
    if (jt < 31) asm volatile("s_waitcnt vmcnt(4) lgkmcnt(0)" ::: "memory");
    else         asm volatile("s_waitcnt vmcnt(0) lgkmcnt(0)" ::: "memory");
    __builtin_amdgcn_s_barrier();
    if (jt < 30) {  // issue B(jt+2)
      const int j0n = (jt + 2) * 64;
      const int p = (jt + 2) % 3;
#pragma unroll
      for (int q = 0; q < 4; ++q) {
        int idx = q * 512 + t;
        int cl = idx >> 3, uu = idx & 7;
        gload_lds16(whtb + (size_t)cl * 2048 + j0n + uu * 8, (char*)&Bb[p][0] + idx * 16);
      }
    }
    if (jt < 31) {  // build P(jt+1)
      const int j0n = (jt + 1) * 64;
      float4 sa = *reinterpret_cast<const float4*>(&s2s[j0n + pj8 * 8]);
      float4 sb = *reinterpret_cast<const float4*>(&s2s[j0n + pj8 * 8 + 4]);
      float p0 = fexp2(fmaxf(C1 + sa.x, fmaf(ALPHA, sa.x, C2)));
      float p1 = fexp2(fmaxf(C1 + sa.y, fmaf(ALPHA, sa.y, C2)));
      float p2 = fexp2(fmaxf(C1 + sa.z, fmaf(ALPHA, sa.z, C2)));
      float p3 = fexp2(fmaxf(C1 + sa.w, fmaf(ALPHA, sa.w, C2)));
      float p4 = fexp2(fmaxf(C1 + sb.x, fmaf(ALPHA, sb.x, C2)));
      float p5 = fexp2(fmaxf(C1 + sb.y, fmaf(ALPHA, sb.y, C2)));
      float p6 = fexp2(fmaxf(C1 + sb.z, fmaf(ALPHA, sb.z, C2)));
      float p7 = fexp2(fmaxf(C1 + sb.w, fmaf(ALPHA, sb.w, C2)));
      half8 ph;
#if __has_builtin(__builtin_amdgcn_cvt_pkrtz)
      fp16x2 q0 = __builtin_amdgcn_cvt_pkrtz(p0, p1);
      fp16x2 q1 = __builtin_amdgcn_cvt_pkrtz(p2, p3);
      fp16x2 q2 = __builtin_amdgcn_cvt_pkrtz(p4, p5);
      fp16x2 q3 = __builtin_amdgcn_cvt_pkrtz(p6, p7);
      ph[0] = (_Float16)q0[0]; ph[1] = (_Float16)q0[1];
      ph[2] = (_Float16)q1[0]; ph[3] = (_Float16)q1[1];
      ph[4] = (_Float16)q2[0]; ph[5] = (_Float16)q2[1];
      ph[6] = (_Float16)q3[0]; ph[7] = (_Float16)q3[1];
#else
      ph[0] = (_Float16)p0; ph[1] = (_Float16)p1; ph[2] = (_Float16)p2; ph[3] = (_Float16)p3;
      ph[4] = (_Float16)p4; ph[5] = (_Float16)p5; ph[6] = (_Float16)p6; ph[7] = (_Float16)p7;
#endif
      *reinterpret_cast<half8*>((char*)&Pb[(jt + 1) & 1][0] + pwoff) = ph;
    }
    // compute tile jt: 4 k-steps of 16, 32x32x16 MFMA
    const char* Bc = (const char*)&Bb[jt % 3][0];
    const char* Pc = (const char*)&Pb[jt & 1][0];
    const int r32 = rg * 32 + (lane & 31);
    const int khalf = (lane >> 5) * 16;  // byte offset of this lane's 8-elem k-slice
#pragma unroll
    for (int ks = 0; ks < 4; ++ks) {
      const int jb = ks * 32 + khalf;
      half8 afr = *reinterpret_cast<const half8*>(Pc + r32 * 128 + (jb ^ ((r32 & 7) << 4)));
      if (cg == 0)  // denominator: ones-column MFMA (row-sums of fp16 P)
        accd = __builtin_amdgcn_mfma_f32_32x32x16_f16(afr, onesb, accd, 0, 0, 0);
#pragma unroll
      for (int ni = 0; ni < 2; ++ni) {
        int cl = cg * 64 + ni * 32 + (lane & 31);
        half8 bfr = *reinterpret_cast<const half8*>(Bc + cl * 128 + (jb ^ ((cl & 7) << 4)));
        acc[ni] = __builtin_amdgcn_mfma_f32_32x32x16_f16(afr, bfr, acc[ni], 0, 0, 0);
      }
    }
  }
  // publish inverted row denominators (col 0 of accd holds row-sums)
  if (cg == 0 && (lane & 31) == 0) {
#pragma unroll
    for (int reg = 0; reg < 16; ++reg) {
      int rr = rg * 32 + (reg & 3) + 8 * (reg >> 2) + 4 * (lane >> 5);
      d_lds[rr] = 1.0f / accd[reg];
    }
  }
  __syncthreads();
  // epilogue: scale, ELU, store fp32
  const int col = cg * 64 + (lane & 31);
#pragma unroll
  for (int reg = 0; reg < 16; ++reg) {
    int rr = rg * 32 + (reg & 3) + 8 * (reg >> 2) + 4 * (lane >> 5);
    float inv = d_lds[rr];
    size_t obase = ((size_t)b * 2048 + i0 + rr) * 256 + col;
#pragma unroll
    for (int ni = 0; ni < 2; ++ni) {
      float v = acc[ni][reg] * inv;
      v = v > 0.f ? v : (__expf(v) - 1.f);
      out[obase + ni * 32] = v;
    }
  }
}

extern "C" void kernel_launch(void* const* d_in, const int* in_sizes, int n_in,
                              void* d_out, int out_size, void* d_ws, size_t ws_size,
                              hipStream_t stream) {
  (void)in_sizes; (void)n_in; (void)out_size; (void)ws_size;
  const float* h = (const float*)d_in[0];
  const float* W = (const float*)d_in[1];
  const float* a1 = (const float*)d_in[2];
  const float* a2 = (const float*)d_in[3];
  float* out = (float*)d_out;
  char* ws = (char*)d_ws;
  _Float16* WhT = (_Float16*)(ws);             // 8*256*2048*2 = 8388608 B (pre-swizzled)
  _Float16* W16 = (_Float16*)(ws + 8388608);   // 262144 B (pre-swizzled)
  float* u1 = (float*)(ws + 8650752);          // 2048 B
  float* u2 = (float*)(ws + 8652800);          // 2048 B
  float* s1 = (float*)(ws + 8654848);          // 65536 B
  float* s2 = (float*)(ws + 8720384);          // 65536 B

  hipLaunchKernelGGL(k_convW, dim3(128), dim3(256), 0, stream, W, W16);
  hipLaunchKernelGGL(k_uvec, dim3(8), dim3(256), 0, stream, W, a1, a2, u1, u2);
  hipLaunchKernelGGL(k_gemm_wh, dim3(512), dim3(256), 0, stream, h, W16, u1, u2, s1, s2, WhT);
  hipLaunchKernelGGL(k_attn, dim3(256), dim3(512), 0, stream, WhT, s1, s2, out);
}